// Round 1
// baseline (383.986 us; speedup 1.0000x reference)
//
#include <hip/hip_runtime.h>
#include <hip/hip_bf16.h>

typedef __attribute__((ext_vector_type(8))) short bf16x8;
typedef __attribute__((ext_vector_type(4))) float f32x4;
typedef unsigned short u16;

typedef const __attribute__((address_space(1))) void* gas_ptr;
typedef __attribute__((address_space(3))) void* las_ptr;

__device__ inline u16 f2bf(float f) {
    __hip_bfloat16 h = __float2bfloat16(f);
    return __builtin_bit_cast(u16, h);
}

__device__ inline void gload16(const u16* g, u16* lds) {
    __builtin_amdgcn_global_load_lds((gas_ptr)g, (las_ptr)lds, 16, 0, 0);
}

// ---------------- LayerNorm (fp32 in -> bf16 out) ----------------
__global__ __launch_bounds__(256) void ln_bf16_kernel(
    const float* __restrict__ x, const float* __restrict__ gamma,
    const float* __restrict__ beta, u16* __restrict__ h) {
    const int C = 1024;
    int row = blockIdx.x;
    int t = threadIdx.x;
    const float4* xr = (const float4*)(x + (size_t)row * C);
    float4 v = xr[t];
    float s  = v.x + v.y + v.z + v.w;
    float s2 = v.x*v.x + v.y*v.y + v.z*v.z + v.w*v.w;
#pragma unroll
    for (int m = 1; m < 64; m <<= 1) {
        s  += __shfl_xor(s, m);
        s2 += __shfl_xor(s2, m);
    }
    __shared__ float red[8];
    if ((t & 63) == 0) { red[t >> 6] = s; red[4 + (t >> 6)] = s2; }
    __syncthreads();
    s  = red[0] + red[1] + red[2] + red[3];
    s2 = red[4] + red[5] + red[6] + red[7];
    float mu  = s * (1.0f / 1024.0f);
    float var = fmaxf(s2 * (1.0f / 1024.0f) - mu * mu, 0.0f);
    float rstd = rsqrtf(var + 1e-5f);
    float4 g  = ((const float4*)gamma)[t];
    float4 bb = ((const float4*)beta)[t];
    ushort4 o;
    o.x = f2bf((v.x - mu) * rstd * g.x + bb.x);
    o.y = f2bf((v.y - mu) * rstd * g.y + bb.y);
    o.z = f2bf((v.z - mu) * rstd * g.z + bb.z);
    o.w = f2bf((v.w - mu) * rstd * g.w + bb.w);
    ((ushort4*)(h + (size_t)row * C))[t] = o;
}

// ---------------- fp32 -> bf16 cast ----------------
__global__ __launch_bounds__(256) void cast_bf16_kernel(
    const float* __restrict__ in, u16* __restrict__ o, int n4) {
    int i = blockIdx.x * blockDim.x + threadIdx.x;
    if (i >= n4) return;
    float4 v = ((const float4*)in)[i];
    ushort4 u;
    u.x = f2bf(v.x); u.y = f2bf(v.y); u.z = f2bf(v.z); u.w = f2bf(v.w);
    ((ushort4*)o)[i] = u;
}

// ---------------- GEMM: C[M,N] = A[M,K] * B[N,K]^T (both bf16 row-major) ----
template<int WRITE_BF16>
__global__ __launch_bounds__(256) void gemm_bt(
    const u16* __restrict__ A, const u16* __restrict__ B,
    void* __restrict__ Cout, int M, int N, int K) {
    __shared__ u16 As[128 * 32];
    __shared__ u16 Bs[128 * 32];
    int t = threadIdx.x;
    int w = t >> 6;
    int l = t & 63;
    int lr = l & 15, lg = l >> 4;
    int mBase = blockIdx.y * 128;
    int nBase = blockIdx.x * 128;
    int wr = w >> 1, wc = w & 1;

    f32x4 zero = {0.f, 0.f, 0.f, 0.f};
    f32x4 acc[4][4];
#pragma unroll
    for (int i = 0; i < 4; i++)
#pragma unroll
        for (int j = 0; j < 4; j++) acc[i][j] = zero;

    for (int k0 = 0; k0 < K; k0 += 32) {
#pragma unroll
        for (int i = 0; i < 2; i++) {
            int fl = i * 256 + t;
            gload16(A + (size_t)(mBase + (fl >> 2)) * K + k0 + (fl & 3) * 8,
                    As + (size_t)(i * 256 + w * 64) * 8);
            gload16(B + (size_t)(nBase + (fl >> 2)) * K + k0 + (fl & 3) * 8,
                    Bs + (size_t)(i * 256 + w * 64) * 8);
        }
        __syncthreads();
        bf16x8 af[4], bfr[4];
#pragma unroll
        for (int m2 = 0; m2 < 4; m2++)
            af[m2] = *(const bf16x8*)&As[(wr * 64 + m2 * 16 + lr) * 32 + lg * 8];
#pragma unroll
        for (int n2 = 0; n2 < 4; n2++)
            bfr[n2] = *(const bf16x8*)&Bs[(wc * 64 + n2 * 16 + lr) * 32 + lg * 8];
#pragma unroll
        for (int m2 = 0; m2 < 4; m2++)
#pragma unroll
            for (int n2 = 0; n2 < 4; n2++)
                acc[m2][n2] = __builtin_amdgcn_mfma_f32_16x16x32_bf16(
                    af[m2], bfr[n2], acc[m2][n2], 0, 0, 0);
        __syncthreads();
    }
#pragma unroll
    for (int m2 = 0; m2 < 4; m2++) {
#pragma unroll
        for (int i = 0; i < 4; i++) {
            int gr = mBase + wr * 64 + m2 * 16 + lg * 4 + i;
#pragma unroll
            for (int n2 = 0; n2 < 4; n2++) {
                int gc = nBase + wc * 64 + n2 * 16 + lr;
                float val = acc[m2][n2][i];
                if (WRITE_BF16)
                    ((u16*)Cout)[(size_t)gr * N + gc] = f2bf(val);
                else
                    ((float*)Cout)[(size_t)gr * N + gc] = val;
            }
        }
    }
}

// ---------------- Flash attention (causal), bf16 ----------------
// qkv: [B*T][3072] rows = b*2048+t, cols: [q 0:1024][k 1024:2048][v 2048:3072]
// o:   [B*T][1024] bf16
__global__ __launch_bounds__(256) void attn_kernel(
    const u16* __restrict__ qkv, u16* __restrict__ o) {
    const int T = 2048;
    const int LD = 3072;
    __shared__ u16 Ks[64][72];        // [kv][dh], +8 pad
    __shared__ u16 Vt[64][72];        // [dh][kv], transposed, +8 pad
    __shared__ u16 Ps[4][16][72];     // per-wave P tile [q][kv]

    int t = threadIdx.x;
    int w = t >> 6, l = t & 63;
    int lr = l & 15, lg = l >> 4;
    int b = blockIdx.x >> 4, h = blockIdx.x & 15;
    int q0 = blockIdx.y * 64;
    size_t base = (size_t)b * T * LD;
    const u16* Qp = qkv + base + (size_t)q0 * LD + h * 64;
    const u16* Kp = qkv + base + 1024 + h * 64;
    const u16* Vp = qkv + base + 2048 + h * 64;

    // Q fragments: wave w owns q rows [q0+w*16, q0+w*16+16)
    bf16x8 qf[2];
    {
        const u16* qr = Qp + (size_t)(w * 16 + lr) * LD + lg * 8;
        qf[0] = *(const bf16x8*)qr;
        qf[1] = *(const bf16x8*)(qr + 32);
    }

    f32x4 zero = {0.f, 0.f, 0.f, 0.f};
    f32x4 oacc[4];
#pragma unroll
    for (int n = 0; n < 4; n++) oacc[n] = zero;
    float mrow[4], lsum[4];
#pragma unroll
    for (int i = 0; i < 4; i++) { mrow[i] = -INFINITY; lsum[i] = 0.f; }

    int qmax_w = q0 + w * 16 + 15;

    for (int j0 = 0; j0 <= q0; j0 += 64) {
        __syncthreads();
        // stage K tile + transposed V tile
#pragma unroll
        for (int i = 0; i < 2; i++) {
            int fl = i * 256 + t;
            int r = fl >> 3, c = (fl & 7) * 8;
            *(uint4*)&Ks[r][c] = *(const uint4*)(Kp + (size_t)(j0 + r) * LD + c);
            union { uint4 v; u16 s[8]; } uu;
            uu.v = *(const uint4*)(Vp + (size_t)(j0 + r) * LD + c);
#pragma unroll
            for (int jj = 0; jj < 8; jj++) Vt[c + jj][r] = uu.s[jj];
        }
        __syncthreads();

        if (j0 <= qmax_w) {
            // S = Q K^T  (16 q rows x 64 kv cols per wave)
            f32x4 sv[4];
#pragma unroll
            for (int n = 0; n < 4; n++) sv[n] = zero;
#pragma unroll
            for (int c2 = 0; c2 < 2; c2++) {
#pragma unroll
                for (int n = 0; n < 4; n++) {
                    bf16x8 kf = *(const bf16x8*)&Ks[n * 16 + lr][c2 * 32 + lg * 8];
                    sv[n] = __builtin_amdgcn_mfma_f32_16x16x32_bf16(qf[c2], kf, sv[n], 0, 0, 0);
                }
            }
            // scale + causal mask + online softmax
            float p[4][4], mnew[4], rs[4];
#pragma unroll
            for (int i = 0; i < 4; i++) {
                int qg = q0 + w * 16 + lg * 4 + i;
                float tm = -INFINITY;
#pragma unroll
                for (int n = 0; n < 4; n++) {
                    int kvg = j0 + n * 16 + lr;
                    float val = sv[n][i] * 0.125f;
                    if (kvg > qg) val = -INFINITY;
                    p[n][i] = val;
                    tm = fmaxf(tm, val);
                }
#pragma unroll
                for (int mk = 1; mk < 16; mk <<= 1) tm = fmaxf(tm, __shfl_xor(tm, mk));
                mnew[i] = fmaxf(mrow[i], tm);
                float sum = 0.f;
#pragma unroll
                for (int n = 0; n < 4; n++) {
                    float e = __expf(p[n][i] - mnew[i]);
                    p[n][i] = e;
                    sum += e;
                }
#pragma unroll
                for (int mk = 1; mk < 16; mk <<= 1) sum += __shfl_xor(sum, mk);
                rs[i] = sum;
            }
#pragma unroll
            for (int i = 0; i < 4; i++) {
                float alpha = __expf(mrow[i] - mnew[i]);
                lsum[i] = lsum[i] * alpha + rs[i];
                mrow[i] = mnew[i];
#pragma unroll
                for (int n = 0; n < 4; n++) {
                    oacc[n][i] *= alpha;
                    Ps[w][lg * 4 + i][n * 16 + lr] = f2bf(p[n][i]);
                }
            }
            // O += P V
#pragma unroll
            for (int c2 = 0; c2 < 2; c2++) {
                bf16x8 pa = *(const bf16x8*)&Ps[w][lr][c2 * 32 + lg * 8];
#pragma unroll
                for (int n = 0; n < 4; n++) {
                    bf16x8 vf = *(const bf16x8*)&Vt[n * 16 + lr][c2 * 32 + lg * 8];
                    oacc[n] = __builtin_amdgcn_mfma_f32_16x16x32_bf16(pa, vf, oacc[n], 0, 0, 0);
                }
            }
        }
    }
    // epilogue: normalize + store
#pragma unroll
    for (int i = 0; i < 4; i++) {
        float inv = 1.0f / lsum[i];
        int qg = q0 + w * 16 + lg * 4 + i;
        size_t orow = ((size_t)b * T + qg) * 1024 + h * 64;
#pragma unroll
        for (int n = 0; n < 4; n++)
            o[orow + n * 16 + lr] = f2bf(oacc[n][i] * inv);
    }
}

extern "C" void kernel_launch(void* const* d_in, const int* in_sizes, int n_in,
                              void* d_out, int out_size, void* d_ws, size_t ws_size,
                              hipStream_t stream) {
    const float* x     = (const float*)d_in[0];
    const float* gamma = (const float*)d_in[1];
    const float* beta  = (const float*)d_in[2];
    const float* wqkv  = (const float*)d_in[3];
    const float* wout  = (const float*)d_in[4];
    float* out = (float*)d_out;

    const int M = 8192;  // 4 * 2048
    char* ws = (char*)d_ws;
    u16* h     = (u16*)ws; ws += (size_t)M * 1024 * 2;
    u16* wqkvb = (u16*)ws; ws += (size_t)3072 * 1024 * 2;
    u16* woutb = (u16*)ws; ws += (size_t)1024 * 1024 * 2;
    u16* qkvb  = (u16*)ws; ws += (size_t)M * 3072 * 2;
    u16* attnb = (u16*)ws; ws += (size_t)M * 1024 * 2;

    ln_bf16_kernel<<<dim3(M), dim3(256), 0, stream>>>(x, gamma, beta, h);
    cast_bf16_kernel<<<dim3((3072 * 1024 / 4 + 255) / 256), dim3(256), 0, stream>>>(
        wqkv, wqkvb, 3072 * 1024 / 4);
    cast_bf16_kernel<<<dim3((1024 * 1024 / 4 + 255) / 256), dim3(256), 0, stream>>>(
        wout, woutb, 1024 * 1024 / 4);
    gemm_bt<1><<<dim3(24, 64), dim3(256), 0, stream>>>(h, wqkvb, (void*)qkvb, M, 3072, 1024);
    attn_kernel<<<dim3(64, 32), dim3(256), 0, stream>>>(qkvb, attnb);
    gemm_bt<0><<<dim3(8, 64), dim3(256), 0, stream>>>(attnb, woutb, (void*)out, M, 1024, 1024);
}

// Round 8
// 295.629 us; speedup vs baseline: 1.2989x; 1.2989x over previous
//
#include <hip/hip_runtime.h>
#include <hip/hip_bf16.h>

typedef __attribute__((ext_vector_type(8))) short bf16x8;
typedef __attribute__((ext_vector_type(4))) float f32x4;
typedef unsigned short u16;

typedef const __attribute__((address_space(1))) void* gas_ptr;
typedef __attribute__((address_space(3))) void* las_ptr;

__device__ inline u16 f2bf(float f) {
    __hip_bfloat16 h = __float2bfloat16(f);
    return __builtin_bit_cast(u16, h);
}

__device__ inline void gload16(const u16* g, u16* lds) {
    __builtin_amdgcn_global_load_lds((gas_ptr)g, (las_ptr)lds, 16, 0, 0);
}

// ---------------- LayerNorm (fp32 in -> bf16 out) ----------------
__global__ __launch_bounds__(256) void ln_bf16_kernel(
    const float* __restrict__ x, const float* __restrict__ gamma,
    const float* __restrict__ beta, u16* __restrict__ h) {
    const int C = 1024;
    int row = blockIdx.x;
    int t = threadIdx.x;
    const float4* xr = (const float4*)(x + (size_t)row * C);
    float4 v = xr[t];
    float s  = v.x + v.y + v.z + v.w;
    float s2 = v.x*v.x + v.y*v.y + v.z*v.z + v.w*v.w;
#pragma unroll
    for (int m = 1; m < 64; m <<= 1) {
        s  += __shfl_xor(s, m);
        s2 += __shfl_xor(s2, m);
    }
    __shared__ float red[8];
    if ((t & 63) == 0) { red[t >> 6] = s; red[4 + (t >> 6)] = s2; }
    __syncthreads();
    s  = red[0] + red[1] + red[2] + red[3];
    s2 = red[4] + red[5] + red[6] + red[7];
    float mu  = s * (1.0f / 1024.0f);
    float var = fmaxf(s2 * (1.0f / 1024.0f) - mu * mu, 0.0f);
    float rstd = rsqrtf(var + 1e-5f);
    float4 g  = ((const float4*)gamma)[t];
    float4 bb = ((const float4*)beta)[t];
    ushort4 o;
    o.x = f2bf((v.x - mu) * rstd * g.x + bb.x);
    o.y = f2bf((v.y - mu) * rstd * g.y + bb.y);
    o.z = f2bf((v.z - mu) * rstd * g.z + bb.z);
    o.w = f2bf((v.w - mu) * rstd * g.w + bb.w);
    ((ushort4*)(h + (size_t)row * C))[t] = o;
}

// ---------------- fp32 -> bf16 cast ----------------
__global__ __launch_bounds__(256) void cast_bf16_kernel(
    const float* __restrict__ in, u16* __restrict__ o, int n4) {
    int i = blockIdx.x * blockDim.x + threadIdx.x;
    if (i >= n4) return;
    float4 v = ((const float4*)in)[i];
    ushort4 u;
    u.x = f2bf(v.x); u.y = f2bf(v.y); u.z = f2bf(v.z); u.w = f2bf(v.w);
    ((ushort4*)o)[i] = u;
}

// ---------------- GEMM: C[M,N] = A[M,K] * B[N,K]^T (both bf16 row-major) ----
template<int WRITE_BF16>
__global__ __launch_bounds__(256) void gemm_bt(
    const u16* __restrict__ A, const u16* __restrict__ B,
    void* __restrict__ Cout, int M, int N, int K) {
    __shared__ u16 As[128 * 32];
    __shared__ u16 Bs[128 * 32];
    int t = threadIdx.x;
    int w = t >> 6;
    int l = t & 63;
    int lr = l & 15, lg = l >> 4;
    int mBase = blockIdx.y * 128;
    int nBase = blockIdx.x * 128;
    int wr = w >> 1, wc = w & 1;

    f32x4 zero = {0.f, 0.f, 0.f, 0.f};
    f32x4 acc[4][4];
#pragma unroll
    for (int i = 0; i < 4; i++)
#pragma unroll
        for (int j = 0; j < 4; j++) acc[i][j] = zero;

    for (int k0 = 0; k0 < K; k0 += 32) {
#pragma unroll
        for (int i = 0; i < 2; i++) {
            int fl = i * 256 + t;
            gload16(A + (size_t)(mBase + (fl >> 2)) * K + k0 + (fl & 3) * 8,
                    As + (size_t)(i * 256 + w * 64) * 8);
            gload16(B + (size_t)(nBase + (fl >> 2)) * K + k0 + (fl & 3) * 8,
                    Bs + (size_t)(i * 256 + w * 64) * 8);
        }
        __syncthreads();
        bf16x8 af[4], bfr[4];
#pragma unroll
        for (int m2 = 0; m2 < 4; m2++)
            af[m2] = *(const bf16x8*)&As[(wr * 64 + m2 * 16 + lr) * 32 + lg * 8];
#pragma unroll
        for (int n2 = 0; n2 < 4; n2++)
            bfr[n2] = *(const bf16x8*)&Bs[(wc * 64 + n2 * 16 + lr) * 32 + lg * 8];
#pragma unroll
        for (int m2 = 0; m2 < 4; m2++)
#pragma unroll
            for (int n2 = 0; n2 < 4; n2++)
                acc[m2][n2] = __builtin_amdgcn_mfma_f32_16x16x32_bf16(
                    af[m2], bfr[n2], acc[m2][n2], 0, 0, 0);
        __syncthreads();
    }
#pragma unroll
    for (int m2 = 0; m2 < 4; m2++) {
#pragma unroll
        for (int i = 0; i < 4; i++) {
            int gr = mBase + wr * 64 + m2 * 16 + lg * 4 + i;
#pragma unroll
            for (int n2 = 0; n2 < 4; n2++) {
                int gc = nBase + wc * 64 + n2 * 16 + lr;
                float val = acc[m2][n2][i];
                if (WRITE_BF16)
                    ((u16*)Cout)[(size_t)gr * N + gc] = f2bf(val);
                else
                    ((float*)Cout)[(size_t)gr * N + gc] = val;
            }
        }
    }
}

// ---------------- Flash attention (causal), bf16, swapped-QK^T ----------------
// qkv: [B*T][3072] rows = b*2048+t, cols: [q 0:1024][k 1024:2048][v 2048:3072]
// o:   [B*T][1024] bf16
//
// 4 waves/block, wave w owns q rows [q0+w*16, q0+w*16+16); lane's softmax row
// is q0+w*16+(l&15).
// K LDS [kv][64] with XOR-swizzled 8-elem chunks: LDS[r][s] = K[r][8*(s^(r&7))..]
//   (linear gload_lds dest + pre-swizzled global source; read with same XOR).
// V LDS subtiled: Vsh[(d>>4)*1024 + kv*16 + (d&15)] = V[kv][d]; PV B-fragment
//   read as scalar u16 (bisection round: no ds_read_b64_tr_b16).
__global__ __launch_bounds__(256) void attn_kernel(
    const u16* __restrict__ qkv, u16* __restrict__ o) {
    const int T = 2048;
    const int LD = 3072;
    __shared__ u16 Ksh[64 * 64];
    __shared__ u16 Vsh[64 * 64];

    int t = threadIdx.x;
    int w = t >> 6, l = t & 63;
    int lr = l & 15, g = l >> 4;
    int b = blockIdx.x >> 4, h = blockIdx.x & 15;
    int q0 = (31 - blockIdx.y) * 64;   // longest blocks launch first
    size_t base = (size_t)b * T * LD;
    const u16* Qp = qkv + base + h * 64;
    const u16* Kp = qkv + base + 1024 + h * 64;
    const u16* Vp = qkv + base + 2048 + h * 64;

    int qrow = q0 + w * 16 + lr;       // softmax row this lane owns
    // Q as B-operand: lane holds Q[qrow][c2*32 + g*8 .. +7]
    bf16x8 qf[2];
    {
        const u16* qr = Qp + (size_t)qrow * LD + g * 8;
        qf[0] = *(const bf16x8*)qr;
        qf[1] = *(const bf16x8*)(qr + 32);
    }

    f32x4 zero = {0.f, 0.f, 0.f, 0.f};
    f32x4 oacc[4];                      // oacc[db][i] = O[q0+w*16+4g+i][db*16+lr]
#pragma unroll
    for (int n = 0; n < 4; n++) oacc[n] = zero;
    float mrow = -INFINITY, lsum = 0.f;

    // staging geometry (per-lane global addresses; LDS bases are wave-uniform)
    int kr = w * 16 + (l >> 3);        // K row for issue i: kr + i*8
    int ks = l & 7;                    // K LDS chunk slot this lane fills
    int vr = l >> 1;                   // V row for issue i: i*32 + vr
    int vc = w * 16 + (l & 1) * 8;     // V d-offset

    for (int j0 = 0; j0 <= q0; j0 += 64) {
        __syncthreads();
#pragma unroll
        for (int i = 0; i < 2; i++) {
            int r = kr + i * 8;
            gload16(Kp + (size_t)(j0 + r) * LD + ((ks ^ (r & 7)) << 3),
                    Ksh + w * 1024 + i * 512);
            gload16(Vp + (size_t)(j0 + i * 32 + vr) * LD + vc,
                    Vsh + w * 1024 + i * 512);
        }
        __syncthreads();

        // S' = K Q^T : lane accumulates S[qrow][kv = j0 + 16n + 4g + i]
        f32x4 sv[4];
#pragma unroll
        for (int n = 0; n < 4; n++) sv[n] = zero;
#pragma unroll
        for (int c2 = 0; c2 < 2; c2++) {
#pragma unroll
            for (int n = 0; n < 4; n++) {
                int row = n * 16 + lr;
                int slot = (c2 * 4 + g) ^ (row & 7);
                bf16x8 kf = *(const bf16x8*)&Ksh[row * 64 + slot * 8];
                sv[n] = __builtin_amdgcn_mfma_f32_16x16x32_bf16(kf, qf[c2], sv[n], 0, 0, 0);
            }
        }

        // online softmax, fully per-lane for q = qrow
        float p[4][4];
        float tmax = -INFINITY;
        bool full = (j0 + 63 <= q0 + w * 16);
#pragma unroll
        for (int n = 0; n < 4; n++)
#pragma unroll
            for (int i = 0; i < 4; i++) {
                float val = sv[n][i] * 0.125f;
                if (!full && (j0 + n * 16 + g * 4 + i > qrow)) val = -INFINITY;
                p[n][i] = val;
                tmax = fmaxf(tmax, val);
            }
        tmax = fmaxf(tmax, __shfl_xor(tmax, 16));
        tmax = fmaxf(tmax, __shfl_xor(tmax, 32));
        float mnew = fmaxf(mrow, tmax);
        float rsum = 0.f;
#pragma unroll
        for (int n = 0; n < 4; n++)
#pragma unroll
            for (int i = 0; i < 4; i++) {
                float e = __expf(p[n][i] - mnew);
                p[n][i] = e;
                rsum += e;
            }
        rsum += __shfl_xor(rsum, 16);
        rsum += __shfl_xor(rsum, 32);
        float alpha = __expf(mrow - mnew);
        lsum = lsum * alpha + rsum;
        mrow = mnew;

        // rescale O accumulator (rows q = 4g+i; fetch alpha from row owners)
        float ao[4];
#pragma unroll
        for (int i = 0; i < 4; i++) ao[i] = __shfl(alpha, g * 4 + i);
#pragma unroll
        for (int db = 0; db < 4; db++)
#pragma unroll
            for (int i = 0; i < 4; i++) oacc[db][i] *= ao[i];

        // pack P to bf16 A-fragments: slot j of pf0 holds kv 4g+j (n=0) and
        // 16+4g+j (n=1); pf1 the same +32. B-fragment below uses the same
        // per-slot kv order, so the MFMA k-permutation cancels.
        bf16x8 pf0, pf1;
#pragma unroll
        for (int j = 0; j < 4; j++) {
            pf0[j]     = (short)f2bf(p[0][j]);
            pf0[4 + j] = (short)f2bf(p[1][j]);
            pf1[j]     = (short)f2bf(p[2][j]);
            pf1[4 + j] = (short)f2bf(p[3][j]);
        }

        // O += P V ; V B-fragment via scalar reads (bisection: no tr_read)
#pragma unroll
        for (int db = 0; db < 4; db++) {
            bf16x8 vb0, vb1;
#pragma unroll
            for (int j = 0; j < 4; j++) {
                vb0[j]     = (short)Vsh[db * 1024 + (4 * g + j) * 16 + lr];
                vb0[4 + j] = (short)Vsh[db * 1024 + (16 + 4 * g + j) * 16 + lr];
                vb1[j]     = (short)Vsh[db * 1024 + (32 + 4 * g + j) * 16 + lr];
                vb1[4 + j] = (short)Vsh[db * 1024 + (48 + 4 * g + j) * 16 + lr];
            }
            oacc[db] = __builtin_amdgcn_mfma_f32_16x16x32_bf16(pf0, vb0, oacc[db], 0, 0, 0);
            oacc[db] = __builtin_amdgcn_mfma_f32_16x16x32_bf16(pf1, vb1, oacc[db], 0, 0, 0);
        }
    }

    // epilogue: normalize + store (row q = q0+w*16+4g+i, col d = h*64+db*16+lr)
    float li[4];
#pragma unroll
    for (int i = 0; i < 4; i++) li[i] = 1.0f / __shfl(lsum, g * 4 + i);
#pragma unroll
    for (int db = 0; db < 4; db++)
#pragma unroll
        for (int i = 0; i < 4; i++) {
            int q = q0 + w * 16 + g * 4 + i;
            o[((size_t)b * T + q) * 1024 + h * 64 + db * 16 + lr] =
                f2bf(oacc[db][i] * li[i]);
        }
}

extern "C" void kernel_launch(void* const* d_in, const int* in_sizes, int n_in,
                              void* d_out, int out_size, void* d_ws, size_t ws_size,
                              hipStream_t stream) {
    const float* x     = (const float*)d_in[0];
    const float* gamma = (const float*)d_in[1];
    const float* beta  = (const float*)d_in[2];
    const float* wqkv  = (const float*)d_in[3];
    const float* wout  = (const float*)d_in[4];
    float* out = (float*)d_out;

    const int M = 8192;  // 4 * 2048
    char* ws = (char*)d_ws;
    u16* h     = (u16*)ws; ws += (size_t)M * 1024 * 2;
    u16* wqkvb = (u16*)ws; ws += (size_t)3072 * 1024 * 2;
    u16* woutb = (u16*)ws; ws += (size_t)1024 * 1024 * 2;
    u16* qkvb  = (u16*)ws; ws += (size_t)M * 3072 * 2;
    u16* attnb = (u16*)ws; ws += (size_t)M * 1024 * 2;

    ln_bf16_kernel<<<dim3(M), dim3(256), 0, stream>>>(x, gamma, beta, h);
    cast_bf16_kernel<<<dim3((3072 * 1024 / 4 + 255) / 256), dim3(256), 0, stream>>>(
        wqkv, wqkvb, 3072 * 1024 / 4);
    cast_bf16_kernel<<<dim3((1024 * 1024 / 4 + 255) / 256), dim3(256), 0, stream>>>(
        wout, woutb, 1024 * 1024 / 4);
    gemm_bt<1><<<dim3(24, 64), dim3(256), 0, stream>>>(h, wqkvb, (void*)qkvb, M, 3072, 1024);
    attn_kernel<<<dim3(64, 32), dim3(256), 0, stream>>>(qkvb, attnb);
    gemm_bt<0><<<dim3(8, 64), dim3(256), 0, stream>>>(attnb, woutb, (void*)out, M, 1024, 1024);
}

// Round 11
// 275.812 us; speedup vs baseline: 1.3922x; 1.0719x over previous
//
#include <hip/hip_runtime.h>
#include <hip/hip_bf16.h>

typedef __attribute__((ext_vector_type(8))) short bf16x8;
typedef __attribute__((ext_vector_type(4))) short bf16x4;
typedef __attribute__((ext_vector_type(4))) float f32x4;
typedef unsigned short u16;

typedef const __attribute__((address_space(1))) void* gas_ptr;
typedef __attribute__((address_space(3))) void* las_ptr;
typedef const __attribute__((address_space(3))) u16* lds_cu16;

__device__ inline u16 f2bf(float f) {
    __hip_bfloat16 h = __float2bfloat16(f);
    return __builtin_bit_cast(u16, h);
}

__device__ inline void gload16(const u16* g, u16* lds) {
    __builtin_amdgcn_global_load_lds((gas_ptr)g, (las_ptr)lds, 16, 0, 0);
}

// ---------------- LayerNorm (fp32 in -> bf16 out) ----------------
__global__ __launch_bounds__(256) void ln_bf16_kernel(
    const float* __restrict__ x, const float* __restrict__ gamma,
    const float* __restrict__ beta, u16* __restrict__ h) {
    const int C = 1024;
    int row = blockIdx.x;
    int t = threadIdx.x;
    const float4* xr = (const float4*)(x + (size_t)row * C);
    float4 v = xr[t];
    float s  = v.x + v.y + v.z + v.w;
    float s2 = v.x*v.x + v.y*v.y + v.z*v.z + v.w*v.w;
#pragma unroll
    for (int m = 1; m < 64; m <<= 1) {
        s  += __shfl_xor(s, m);
        s2 += __shfl_xor(s2, m);
    }
    __shared__ float red[8];
    if ((t & 63) == 0) { red[t >> 6] = s; red[4 + (t >> 6)] = s2; }
    __syncthreads();
    s  = red[0] + red[1] + red[2] + red[3];
    s2 = red[4] + red[5] + red[6] + red[7];
    float mu  = s * (1.0f / 1024.0f);
    float var = fmaxf(s2 * (1.0f / 1024.0f) - mu * mu, 0.0f);
    float rstd = rsqrtf(var + 1e-5f);
    float4 g  = ((const float4*)gamma)[t];
    float4 bb = ((const float4*)beta)[t];
    ushort4 o;
    o.x = f2bf((v.x - mu) * rstd * g.x + bb.x);
    o.y = f2bf((v.y - mu) * rstd * g.y + bb.y);
    o.z = f2bf((v.z - mu) * rstd * g.z + bb.z);
    o.w = f2bf((v.w - mu) * rstd * g.w + bb.w);
    ((ushort4*)(h + (size_t)row * C))[t] = o;
}

// ---------------- fp32 -> bf16 cast ----------------
__global__ __launch_bounds__(256) void cast_bf16_kernel(
    const float* __restrict__ in, u16* __restrict__ o, int n4) {
    int i = blockIdx.x * blockDim.x + threadIdx.x;
    if (i >= n4) return;
    float4 v = ((const float4*)in)[i];
    ushort4 u;
    u.x = f2bf(v.x); u.y = f2bf(v.y); u.z = f2bf(v.z); u.w = f2bf(v.w);
    ((ushort4*)o)[i] = u;
}

// ---------------- GEMM: C[M,N] = A[M,K] * B[N,K]^T (both bf16 row-major) ----
template<int WRITE_BF16>
__global__ __launch_bounds__(256) void gemm_bt(
    const u16* __restrict__ A, const u16* __restrict__ B,
    void* __restrict__ Cout, int M, int N, int K) {
    __shared__ u16 As[128 * 32];
    __shared__ u16 Bs[128 * 32];
    int t = threadIdx.x;
    int w = t >> 6;
    int l = t & 63;
    int lr = l & 15, lg = l >> 4;
    int mBase = blockIdx.y * 128;
    int nBase = blockIdx.x * 128;
    int wr = w >> 1, wc = w & 1;

    f32x4 zero = {0.f, 0.f, 0.f, 0.f};
    f32x4 acc[4][4];
#pragma unroll
    for (int i = 0; i < 4; i++)
#pragma unroll
        for (int j = 0; j < 4; j++) acc[i][j] = zero;

    for (int k0 = 0; k0 < K; k0 += 32) {
#pragma unroll
        for (int i = 0; i < 2; i++) {
            int fl = i * 256 + t;
            gload16(A + (size_t)(mBase + (fl >> 2)) * K + k0 + (fl & 3) * 8,
                    As + (size_t)(i * 256 + w * 64) * 8);
            gload16(B + (size_t)(nBase + (fl >> 2)) * K + k0 + (fl & 3) * 8,
                    Bs + (size_t)(i * 256 + w * 64) * 8);
        }
        __syncthreads();
        bf16x8 af[4], bfr[4];
#pragma unroll
        for (int m2 = 0; m2 < 4; m2++)
            af[m2] = *(const bf16x8*)&As[(wr * 64 + m2 * 16 + lr) * 32 + lg * 8];
#pragma unroll
        for (int n2 = 0; n2 < 4; n2++)
            bfr[n2] = *(const bf16x8*)&Bs[(wc * 64 + n2 * 16 + lr) * 32 + lg * 8];
#pragma unroll
        for (int m2 = 0; m2 < 4; m2++)
#pragma unroll
            for (int n2 = 0; n2 < 4; n2++)
                acc[m2][n2] = __builtin_amdgcn_mfma_f32_16x16x32_bf16(
                    af[m2], bfr[n2], acc[m2][n2], 0, 0, 0);
        __syncthreads();
    }
#pragma unroll
    for (int m2 = 0; m2 < 4; m2++) {
#pragma unroll
        for (int i = 0; i < 4; i++) {
            int gr = mBase + wr * 64 + m2 * 16 + lg * 4 + i;
#pragma unroll
            for (int n2 = 0; n2 < 4; n2++) {
                int gc = nBase + wc * 64 + n2 * 16 + lr;
                float val = acc[m2][n2][i];
                if (WRITE_BF16)
                    ((u16*)Cout)[(size_t)gr * N + gc] = f2bf(val);
                else
                    ((float*)Cout)[(size_t)gr * N + gc] = val;
            }
        }
    }
}

// ---------------- Flash attention (causal), bf16, swapped-QK^T ----------------
// qkv: [B*T][3072] rows = b*2048+t, cols: [q 0:1024][k 1024:2048][v 2048:3072]
// o:   [B*T][1024] bf16
//
// 4 waves/block, wave w owns q rows [q0+w*16, q0+w*16+16); lane's softmax row
// is q0+w*16+(l&15).
// K LDS [kv][64] with XOR-swizzled 8-elem chunks (R8-verified).
// V LDS subtiled: Vsh[(d>>4)*1024 + kv*16 + (d&15)] = V[kv][d] (R8-verified).
// PV B-fragment via ds_read_b64_tr_b16, CORRECTED semantics: cross-lane
// transpose gather. With per-lane LINEAR address a_l = Vsh + 4*l elements and
// uniform offset db*2048 + n*512 bytes, lane l=(16g+lr) elem j receives
// element (db*1024 + 256n) + 64g + 16j + lr = V[16n+4g+j][db*16+lr]
// (m156's formula; value-identical to R8's scalar path).
__global__ __launch_bounds__(256) void attn_kernel(
    const u16* __restrict__ qkv, u16* __restrict__ o) {
    const int T = 2048;
    const int LD = 3072;
    __shared__ u16 Ksh[64 * 64];
    __shared__ u16 Vsh[64 * 64];

    int t = threadIdx.x;
    int w = t >> 6, l = t & 63;
    int lr = l & 15, g = l >> 4;
    int b = blockIdx.x >> 4, h = blockIdx.x & 15;
    int q0 = (31 - blockIdx.y) * 64;   // longest blocks launch first
    size_t base = (size_t)b * T * LD;
    const u16* Qp = qkv + base + h * 64;
    const u16* Kp = qkv + base + 1024 + h * 64;
    const u16* Vp = qkv + base + 2048 + h * 64;

    int qrow = q0 + w * 16 + lr;       // softmax row this lane owns
    // Q as B-operand: lane holds Q[qrow][c2*32 + g*8 .. +7]
    bf16x8 qf[2];
    {
        const u16* qr = Qp + (size_t)qrow * LD + g * 8;
        qf[0] = *(const bf16x8*)qr;
        qf[1] = *(const bf16x8*)(qr + 32);
    }

    f32x4 zero = {0.f, 0.f, 0.f, 0.f};
    f32x4 oacc[4];                      // oacc[db][i] = O[q0+w*16+4g+i][db*16+lr]
#pragma unroll
    for (int n = 0; n < 4; n++) oacc[n] = zero;
    float mrow = -INFINITY, lsum = 0.f;

    // staging geometry (per-lane global addresses; LDS bases are wave-uniform)
    int kr = w * 16 + (l >> 3);        // K row for issue i: kr + i*8
    int ks = l & 7;                    // K LDS chunk slot this lane fills
    int vr = l >> 1;                   // V row for issue i: i*32 + vr
    int vc = w * 16 + (l & 1) * 8;     // V d-offset
    lds_cu16 vtr = (lds_cu16)(Vsh + l * 4);   // LINEAR b64 slot (corrected)

    for (int j0 = 0; j0 <= q0; j0 += 64) {
        __syncthreads();
#pragma unroll
        for (int i = 0; i < 2; i++) {
            int r = kr + i * 8;
            gload16(Kp + (size_t)(j0 + r) * LD + ((ks ^ (r & 7)) << 3),
                    Ksh + w * 1024 + i * 512);
            gload16(Vp + (size_t)(j0 + i * 32 + vr) * LD + vc,
                    Vsh + w * 1024 + i * 512);
        }
        __syncthreads();

        // S' = K Q^T : lane accumulates S[qrow][kv = j0 + 16n + 4g + i]
        f32x4 sv[4];
#pragma unroll
        for (int n = 0; n < 4; n++) sv[n] = zero;
#pragma unroll
        for (int c2 = 0; c2 < 2; c2++) {
#pragma unroll
            for (int n = 0; n < 4; n++) {
                int row = n * 16 + lr;
                int slot = (c2 * 4 + g) ^ (row & 7);
                bf16x8 kf = *(const bf16x8*)&Ksh[row * 64 + slot * 8];
                sv[n] = __builtin_amdgcn_mfma_f32_16x16x32_bf16(kf, qf[c2], sv[n], 0, 0, 0);
            }
        }

        // online softmax, fully per-lane for q = qrow
        float p[4][4];
        float tmax = -INFINITY;
        bool full = (j0 + 63 <= q0 + w * 16);
#pragma unroll
        for (int n = 0; n < 4; n++)
#pragma unroll
            for (int i = 0; i < 4; i++) {
                float val = sv[n][i] * 0.125f;
                if (!full && (j0 + n * 16 + g * 4 + i > qrow)) val = -INFINITY;
                p[n][i] = val;
                tmax = fmaxf(tmax, val);
            }
        tmax = fmaxf(tmax, __shfl_xor(tmax, 16));
        tmax = fmaxf(tmax, __shfl_xor(tmax, 32));
        float mnew = fmaxf(mrow, tmax);
        float rsum = 0.f;
#pragma unroll
        for (int n = 0; n < 4; n++)
#pragma unroll
            for (int i = 0; i < 4; i++) {
                float e = __expf(p[n][i] - mnew);
                p[n][i] = e;
                rsum += e;
            }
        rsum += __shfl_xor(rsum, 16);
        rsum += __shfl_xor(rsum, 32);
        float alpha = __expf(mrow - mnew);
        lsum = lsum * alpha + rsum;
        mrow = mnew;

        // rescale O accumulator (rows q = 4g+i; fetch alpha from row owners)
        float ao[4];
#pragma unroll
        for (int i = 0; i < 4; i++) ao[i] = __shfl(alpha, g * 4 + i);
#pragma unroll
        for (int db = 0; db < 4; db++)
#pragma unroll
            for (int i = 0; i < 4; i++) oacc[db][i] *= ao[i];

        // pack P to bf16 A-fragments: slot j of pf0 holds kv 4g+j (n=0) and
        // 16+4g+j (n=1); pf1 the same +32. B-fragment below uses the same
        // per-slot kv order, so the MFMA k-permutation cancels.
        bf16x8 pf0, pf1;
#pragma unroll
        for (int j = 0; j < 4; j++) {
            pf0[j]     = (short)f2bf(p[0][j]);
            pf0[4 + j] = (short)f2bf(p[1][j]);
            pf1[j]     = (short)f2bf(p[2][j]);
            pf1[4 + j] = (short)f2bf(p[3][j]);
        }

        // O += P V ; V B-fragment via hardware-transpose reads (linear base)
#pragma unroll
        for (int db = 0; db < 4; db++) {
            bf16x4 t0, t1, t2, t3;
            asm volatile("ds_read_b64_tr_b16 %0, %1 offset:%2"
                         : "=v"(t0) : "v"(vtr), "i"(db * 2048 + 0));
            asm volatile("ds_read_b64_tr_b16 %0, %1 offset:%2"
                         : "=v"(t1) : "v"(vtr), "i"(db * 2048 + 512));
            asm volatile("ds_read_b64_tr_b16 %0, %1 offset:%2"
                         : "=v"(t2) : "v"(vtr), "i"(db * 2048 + 1024));
            asm volatile("ds_read_b64_tr_b16 %0, %1 offset:%2"
                         : "=v"(t3) : "v"(vtr), "i"(db * 2048 + 1536));
            asm volatile("s_waitcnt lgkmcnt(0)" ::: "memory");
            __builtin_amdgcn_sched_barrier(0);
            bf16x8 vb0, vb1;
#pragma unroll
            for (int j = 0; j < 4; j++) {
                vb0[j] = t0[j]; vb0[4 + j] = t1[j];
                vb1[j] = t2[j]; vb1[4 + j] = t3[j];
            }
            oacc[db] = __builtin_amdgcn_mfma_f32_16x16x32_bf16(pf0, vb0, oacc[db], 0, 0, 0);
            oacc[db] = __builtin_amdgcn_mfma_f32_16x16x32_bf16(pf1, vb1, oacc[db], 0, 0, 0);
        }
    }

    // epilogue: normalize + store (row q = q0+w*16+4g+i, col d = h*64+db*16+lr)
    float li[4];
#pragma unroll
    for (int i = 0; i < 4; i++) li[i] = 1.0f / __shfl(lsum, g * 4 + i);
#pragma unroll
    for (int db = 0; db < 4; db++)
#pragma unroll
        for (int i = 0; i < 4; i++) {
            int q = q0 + w * 16 + g * 4 + i;
            o[((size_t)b * T + q) * 1024 + h * 64 + db * 16 + lr] =
                f2bf(oacc[db][i] * li[i]);
        }
}

extern "C" void kernel_launch(void* const* d_in, const int* in_sizes, int n_in,
                              void* d_out, int out_size, void* d_ws, size_t ws_size,
                              hipStream_t stream) {
    const float* x     = (const float*)d_in[0];
    const float* gamma = (const float*)d_in[1];
    const float* beta  = (const float*)d_in[2];
    const float* wqkv  = (const float*)d_in[3];
    const float* wout  = (const float*)d_in[4];
    float* out = (float*)d_out;

    const int M = 8192;  // 4 * 2048
    char* ws = (char*)d_ws;
    u16* h     = (u16*)ws; ws += (size_t)M * 1024 * 2;
    u16* wqkvb = (u16*)ws; ws += (size_t)3072 * 1024 * 2;
    u16* woutb = (u16*)ws; ws += (size_t)1024 * 1024 * 2;
    u16* qkvb  = (u16*)ws; ws += (size_t)M * 3072 * 2;
    u16* attnb = (u16*)ws; ws += (size_t)M * 1024 * 2;

    ln_bf16_kernel<<<dim3(M), dim3(256), 0, stream>>>(x, gamma, beta, h);
    cast_bf16_kernel<<<dim3((3072 * 1024 / 4 + 255) / 256), dim3(256), 0, stream>>>(
        wqkv, wqkvb, 3072 * 1024 / 4);
    cast_bf16_kernel<<<dim3((1024 * 1024 / 4 + 255) / 256), dim3(256), 0, stream>>>(
        wout, woutb, 1024 * 1024 / 4);
    gemm_bt<1><<<dim3(24, 64), dim3(256), 0, stream>>>(h, wqkvb, (void*)qkvb, M, 3072, 1024);
    attn_kernel<<<dim3(64, 32), dim3(256), 0, stream>>>(qkvb, attnb);
    gemm_bt<0><<<dim3(8, 64), dim3(256), 0, stream>>>(attnb, woutb, (void*)out, M, 1024, 1024);
}

// Round 12
// 271.782 us; speedup vs baseline: 1.4128x; 1.0148x over previous
//
#include <hip/hip_runtime.h>
#include <hip/hip_bf16.h>

typedef __attribute__((ext_vector_type(8))) short bf16x8;
typedef __attribute__((ext_vector_type(4))) short bf16x4;
typedef __attribute__((ext_vector_type(4))) float f32x4;
typedef unsigned short u16;

typedef const __attribute__((address_space(1))) void* gas_ptr;
typedef __attribute__((address_space(3))) void* las_ptr;
typedef const __attribute__((address_space(3))) u16* lds_cu16;

__device__ inline u16 f2bf(float f) {
    __hip_bfloat16 h = __float2bfloat16(f);
    return __builtin_bit_cast(u16, h);
}

__device__ inline float bf2f(u16 u) {
    unsigned int x = ((unsigned int)u) << 16;
    return __builtin_bit_cast(float, x);
}

__device__ inline void gload16(const u16* g, u16* lds) {
    __builtin_amdgcn_global_load_lds((gas_ptr)g, (las_ptr)lds, 16, 0, 0);
}

// ---------------- LayerNorm (fp32 in -> bf16 out) ----------------
__global__ __launch_bounds__(256) void ln_bf16_kernel(
    const float* __restrict__ x, const float* __restrict__ gamma,
    const float* __restrict__ beta, u16* __restrict__ h) {
    const int C = 1024;
    int row = blockIdx.x;
    int t = threadIdx.x;
    const float4* xr = (const float4*)(x + (size_t)row * C);
    float4 v = xr[t];
    float s  = v.x + v.y + v.z + v.w;
    float s2 = v.x*v.x + v.y*v.y + v.z*v.z + v.w*v.w;
#pragma unroll
    for (int m = 1; m < 64; m <<= 1) {
        s  += __shfl_xor(s, m);
        s2 += __shfl_xor(s2, m);
    }
    __shared__ float red[8];
    if ((t & 63) == 0) { red[t >> 6] = s; red[4 + (t >> 6)] = s2; }
    __syncthreads();
    s  = red[0] + red[1] + red[2] + red[3];
    s2 = red[4] + red[5] + red[6] + red[7];
    float mu  = s * (1.0f / 1024.0f);
    float var = fmaxf(s2 * (1.0f / 1024.0f) - mu * mu, 0.0f);
    float rstd = rsqrtf(var + 1e-5f);
    float4 g  = ((const float4*)gamma)[t];
    float4 bb = ((const float4*)beta)[t];
    ushort4 o;
    o.x = f2bf((v.x - mu) * rstd * g.x + bb.x);
    o.y = f2bf((v.y - mu) * rstd * g.y + bb.y);
    o.z = f2bf((v.z - mu) * rstd * g.z + bb.z);
    o.w = f2bf((v.w - mu) * rstd * g.w + bb.w);
    ((ushort4*)(h + (size_t)row * C))[t] = o;
}

// ---------------- fp32 -> bf16 cast ----------------
__global__ __launch_bounds__(256) void cast_bf16_kernel(
    const float* __restrict__ in, u16* __restrict__ o, int n4) {
    int i = blockIdx.x * blockDim.x + threadIdx.x;
    if (i >= n4) return;
    float4 v = ((const float4*)in)[i];
    ushort4 u;
    u.x = f2bf(v.x); u.y = f2bf(v.y); u.z = f2bf(v.z); u.w = f2bf(v.w);
    ((ushort4*)o)[i] = u;
}

// ---------------- GEMM: C[M,N] = A[M,K] * B[N,K]^T (both bf16 row-major) ----
template<int WRITE_BF16>
__global__ __launch_bounds__(256) void gemm_bt(
    const u16* __restrict__ A, const u16* __restrict__ B,
    void* __restrict__ Cout, int M, int N, int K) {
    __shared__ u16 As[128 * 32];
    __shared__ u16 Bs[128 * 32];
    int t = threadIdx.x;
    int w = t >> 6;
    int l = t & 63;
    int lr = l & 15, lg = l >> 4;
    int mBase = blockIdx.y * 128;
    int nBase = blockIdx.x * 128;
    int wr = w >> 1, wc = w & 1;

    f32x4 zero = {0.f, 0.f, 0.f, 0.f};
    f32x4 acc[4][4];
#pragma unroll
    for (int i = 0; i < 4; i++)
#pragma unroll
        for (int j = 0; j < 4; j++) acc[i][j] = zero;

    for (int k0 = 0; k0 < K; k0 += 32) {
#pragma unroll
        for (int i = 0; i < 2; i++) {
            int fl = i * 256 + t;
            gload16(A + (size_t)(mBase + (fl >> 2)) * K + k0 + (fl & 3) * 8,
                    As + (size_t)(i * 256 + w * 64) * 8);
            gload16(B + (size_t)(nBase + (fl >> 2)) * K + k0 + (fl & 3) * 8,
                    Bs + (size_t)(i * 256 + w * 64) * 8);
        }
        __syncthreads();
        bf16x8 af[4], bfr[4];
#pragma unroll
        for (int m2 = 0; m2 < 4; m2++)
            af[m2] = *(const bf16x8*)&As[(wr * 64 + m2 * 16 + lr) * 32 + lg * 8];
#pragma unroll
        for (int n2 = 0; n2 < 4; n2++)
            bfr[n2] = *(const bf16x8*)&Bs[(wc * 64 + n2 * 16 + lr) * 32 + lg * 8];
#pragma unroll
        for (int m2 = 0; m2 < 4; m2++)
#pragma unroll
            for (int n2 = 0; n2 < 4; n2++)
                acc[m2][n2] = __builtin_amdgcn_mfma_f32_16x16x32_bf16(
                    af[m2], bfr[n2], acc[m2][n2], 0, 0, 0);
        __syncthreads();
    }
#pragma unroll
    for (int m2 = 0; m2 < 4; m2++) {
#pragma unroll
        for (int i = 0; i < 4; i++) {
            int gr = mBase + wr * 64 + m2 * 16 + lg * 4 + i;
#pragma unroll
            for (int n2 = 0; n2 < 4; n2++) {
                int gc = nBase + wc * 64 + n2 * 16 + lr;
                float val = acc[m2][n2][i];
                if (WRITE_BF16)
                    ((u16*)Cout)[(size_t)gr * N + gc] = f2bf(val);
                else
                    ((float*)Cout)[(size_t)gr * N + gc] = val;
            }
        }
    }
}

// ---------------- Flash attention (causal), bf16, swapped-QK^T ----------------
// qkv: [B*T][3072] rows = b*2048+t, cols: [q 0:1024][k 1024:2048][v 2048:3072]
// o:   [B*T][1024] bf16
//
// R11-verified structure. This round (R12): two VALU cuts, attn-only:
//  1) Q pre-scaled by 0.125 at load (exact in bf16) -> no per-tile S scaling.
//  2) T13 defer-max (THR=8): skip alpha/rescale when row max grew <= 8.
__global__ __launch_bounds__(256) void attn_kernel(
    const u16* __restrict__ qkv, u16* __restrict__ o) {
    const int T = 2048;
    const int LD = 3072;
    __shared__ u16 Ksh[64 * 64];
    __shared__ u16 Vsh[64 * 64];

    int t = threadIdx.x;
    int w = t >> 6, l = t & 63;
    int lr = l & 15, g = l >> 4;
    int b = blockIdx.x >> 4, h = blockIdx.x & 15;
    int q0 = (31 - blockIdx.y) * 64;   // longest blocks launch first
    size_t base = (size_t)b * T * LD;
    const u16* Qp = qkv + base + h * 64;
    const u16* Kp = qkv + base + 1024 + h * 64;
    const u16* Vp = qkv + base + 2048 + h * 64;

    int qrow = q0 + w * 16 + lr;       // softmax row this lane owns
    // Q as B-operand, pre-scaled by 1/8 (exact: power-of-2 exponent shift)
    bf16x8 qf[2];
    {
        const u16* qr = Qp + (size_t)qrow * LD + g * 8;
        qf[0] = *(const bf16x8*)qr;
        qf[1] = *(const bf16x8*)(qr + 32);
#pragma unroll
        for (int j = 0; j < 8; j++) {
            qf[0][j] = (short)f2bf(bf2f((u16)qf[0][j]) * 0.125f);
            qf[1][j] = (short)f2bf(bf2f((u16)qf[1][j]) * 0.125f);
        }
    }

    f32x4 zero = {0.f, 0.f, 0.f, 0.f};
    f32x4 oacc[4];                      // oacc[db][i] = O[q0+w*16+4g+i][db*16+lr]
#pragma unroll
    for (int n = 0; n < 4; n++) oacc[n] = zero;
    float mrow = -INFINITY, lsum = 0.f;

    // staging geometry (per-lane global addresses; LDS bases are wave-uniform)
    int kr = w * 16 + (l >> 3);        // K row for issue i: kr + i*8
    int ks = l & 7;                    // K LDS chunk slot this lane fills
    int vr = l >> 1;                   // V row for issue i: i*32 + vr
    int vc = w * 16 + (l & 1) * 8;     // V d-offset
    lds_cu16 vtr = (lds_cu16)(Vsh + l * 4);   // linear b64 slot (R11-verified)

    for (int j0 = 0; j0 <= q0; j0 += 64) {
        __syncthreads();
#pragma unroll
        for (int i = 0; i < 2; i++) {
            int r = kr + i * 8;
            gload16(Kp + (size_t)(j0 + r) * LD + ((ks ^ (r & 7)) << 3),
                    Ksh + w * 1024 + i * 512);
            gload16(Vp + (size_t)(j0 + i * 32 + vr) * LD + vc,
                    Vsh + w * 1024 + i * 512);
        }
        __syncthreads();

        // S' = K Q^T : lane accumulates S[qrow][kv = j0 + 16n + 4g + i]
        f32x4 sv[4];
#pragma unroll
        for (int n = 0; n < 4; n++) sv[n] = zero;
#pragma unroll
        for (int c2 = 0; c2 < 2; c2++) {
#pragma unroll
            for (int n = 0; n < 4; n++) {
                int row = n * 16 + lr;
                int slot = (c2 * 4 + g) ^ (row & 7);
                bf16x8 kf = *(const bf16x8*)&Ksh[row * 64 + slot * 8];
                sv[n] = __builtin_amdgcn_mfma_f32_16x16x32_bf16(kf, qf[c2], sv[n], 0, 0, 0);
            }
        }

        // online softmax, per-lane for q = qrow (S already scaled via Q)
        float p[4][4];
        float tmax = -INFINITY;
        bool full = (j0 + 63 <= q0 + w * 16);
#pragma unroll
        for (int n = 0; n < 4; n++)
#pragma unroll
            for (int i = 0; i < 4; i++) {
                float val = sv[n][i];
                if (!full && (j0 + n * 16 + g * 4 + i > qrow)) val = -INFINITY;
                p[n][i] = val;
                tmax = fmaxf(tmax, val);
            }
        tmax = fmaxf(tmax, __shfl_xor(tmax, 16));
        tmax = fmaxf(tmax, __shfl_xor(tmax, 32));

        // T13 defer-max: skip rescale when row max grew by <= 8
        bool defer = __all(tmax - mrow <= 8.0f);
        float mnew = defer ? mrow : fmaxf(mrow, tmax);
        float rsum = 0.f;
#pragma unroll
        for (int n = 0; n < 4; n++)
#pragma unroll
            for (int i = 0; i < 4; i++) {
                float e = __expf(p[n][i] - mnew);
                p[n][i] = e;
                rsum += e;
            }
        rsum += __shfl_xor(rsum, 16);
        rsum += __shfl_xor(rsum, 32);
        if (defer) {
            lsum += rsum;
        } else {
            float alpha = __expf(mrow - mnew);
            lsum = lsum * alpha + rsum;
            mrow = mnew;
            float ao[4];
#pragma unroll
            for (int i = 0; i < 4; i++) ao[i] = __shfl(alpha, g * 4 + i);
#pragma unroll
            for (int db = 0; db < 4; db++)
#pragma unroll
                for (int i = 0; i < 4; i++) oacc[db][i] *= ao[i];
        }

        // pack P to bf16 A-fragments: slot j of pf0 holds kv 4g+j (n=0) and
        // 16+4g+j (n=1); pf1 the same +32 (k-permutation cancels with B).
        bf16x8 pf0, pf1;
#pragma unroll
        for (int j = 0; j < 4; j++) {
            pf0[j]     = (short)f2bf(p[0][j]);
            pf0[4 + j] = (short)f2bf(p[1][j]);
            pf1[j]     = (short)f2bf(p[2][j]);
            pf1[4 + j] = (short)f2bf(p[3][j]);
        }

        // O += P V ; V B-fragment via hardware-transpose reads (linear base)
#pragma unroll
        for (int db = 0; db < 4; db++) {
            bf16x4 t0, t1, t2, t3;
            asm volatile("ds_read_b64_tr_b16 %0, %1 offset:%2"
                         : "=v"(t0) : "v"(vtr), "i"(db * 2048 + 0));
            asm volatile("ds_read_b64_tr_b16 %0, %1 offset:%2"
                         : "=v"(t1) : "v"(vtr), "i"(db * 2048 + 512));
            asm volatile("ds_read_b64_tr_b16 %0, %1 offset:%2"
                         : "=v"(t2) : "v"(vtr), "i"(db * 2048 + 1024));
            asm volatile("ds_read_b64_tr_b16 %0, %1 offset:%2"
                         : "=v"(t3) : "v"(vtr), "i"(db * 2048 + 1536));
            asm volatile("s_waitcnt lgkmcnt(0)" ::: "memory");
            __builtin_amdgcn_sched_barrier(0);
            bf16x8 vb0, vb1;
#pragma unroll
            for (int j = 0; j < 4; j++) {
                vb0[j] = t0[j]; vb0[4 + j] = t1[j];
                vb1[j] = t2[j]; vb1[4 + j] = t3[j];
            }
            oacc[db] = __builtin_amdgcn_mfma_f32_16x16x32_bf16(pf0, vb0, oacc[db], 0, 0, 0);
            oacc[db] = __builtin_amdgcn_mfma_f32_16x16x32_bf16(pf1, vb1, oacc[db], 0, 0, 0);
        }
    }

    // epilogue: normalize + store (row q = q0+w*16+4g+i, col d = h*64+db*16+lr)
    float li[4];
#pragma unroll
    for (int i = 0; i < 4; i++) li[i] = 1.0f / __shfl(lsum, g * 4 + i);
#pragma unroll
    for (int db = 0; db < 4; db++)
#pragma unroll
        for (int i = 0; i < 4; i++) {
            int q = q0 + w * 16 + g * 4 + i;
            o[((size_t)b * T + q) * 1024 + h * 64 + db * 16 + lr] =
                f2bf(oacc[db][i] * li[i]);
        }
}

extern "C" void kernel_launch(void* const* d_in, const int* in_sizes, int n_in,
                              void* d_out, int out_size, void* d_ws, size_t ws_size,
                              hipStream_t stream) {
    const float* x     = (const float*)d_in[0];
    const float* gamma = (const float*)d_in[1];
    const float* beta  = (const float*)d_in[2];
    const float* wqkv  = (const float*)d_in[3];
    const float* wout  = (const float*)d_in[4];
    float* out = (float*)d_out;

    const int M = 8192;  // 4 * 2048
    char* ws = (char*)d_ws;
    u16* h     = (u16*)ws; ws += (size_t)M * 1024 * 2;
    u16* wqkvb = (u16*)ws; ws += (size_t)3072 * 1024 * 2;
    u16* woutb = (u16*)ws; ws += (size_t)1024 * 1024 * 2;
    u16* qkvb  = (u16*)ws; ws += (size_t)M * 3072 * 2;
    u16* attnb = (u16*)ws; ws += (size_t)M * 1024 * 2;

    ln_bf16_kernel<<<dim3(M), dim3(256), 0, stream>>>(x, gamma, beta, h);
    cast_bf16_kernel<<<dim3((3072 * 1024 / 4 + 255) / 256), dim3(256), 0, stream>>>(
        wqkv, wqkvb, 3072 * 1024 / 4);
    cast_bf16_kernel<<<dim3((1024 * 1024 / 4 + 255) / 256), dim3(256), 0, stream>>>(
        wout, woutb, 1024 * 1024 / 4);
    gemm_bt<1><<<dim3(24, 64), dim3(256), 0, stream>>>(h, wqkvb, (void*)qkvb, M, 3072, 1024);
    attn_kernel<<<dim3(64, 32), dim3(256), 0, stream>>>(qkvb, attnb);
    gemm_bt<0><<<dim3(8, 64), dim3(256), 0, stream>>>(attnb, woutb, (void*)out, M, 1024, 1024);
}

// Round 13
// 269.572 us; speedup vs baseline: 1.4244x; 1.0082x over previous
//
#include <hip/hip_runtime.h>
#include <hip/hip_bf16.h>

typedef __attribute__((ext_vector_type(8))) short bf16x8;
typedef __attribute__((ext_vector_type(4))) short bf16x4;
typedef __attribute__((ext_vector_type(4))) float f32x4;
typedef unsigned short u16;

typedef const __attribute__((address_space(1))) void* gas_ptr;
typedef __attribute__((address_space(3))) void* las_ptr;
typedef const __attribute__((address_space(3))) u16* lds_cu16;

__device__ inline u16 f2bf(float f) {
    __hip_bfloat16 h = __float2bfloat16(f);
    return __builtin_bit_cast(u16, h);
}

__device__ inline float bf2f(u16 u) {
    unsigned int x = ((unsigned int)u) << 16;
    return __builtin_bit_cast(float, x);
}

__device__ inline void gload16(const u16* g, u16* lds) {
    __builtin_amdgcn_global_load_lds((gas_ptr)g, (las_ptr)lds, 16, 0, 0);
}

// ---------------- LayerNorm (fp32 in -> bf16 out) ----------------
__global__ __launch_bounds__(256) void ln_bf16_kernel(
    const float* __restrict__ x, const float* __restrict__ gamma,
    const float* __restrict__ beta, u16* __restrict__ h) {
    const int C = 1024;
    int row = blockIdx.x;
    int t = threadIdx.x;
    const float4* xr = (const float4*)(x + (size_t)row * C);
    float4 v = xr[t];
    float s  = v.x + v.y + v.z + v.w;
    float s2 = v.x*v.x + v.y*v.y + v.z*v.z + v.w*v.w;
#pragma unroll
    for (int m = 1; m < 64; m <<= 1) {
        s  += __shfl_xor(s, m);
        s2 += __shfl_xor(s2, m);
    }
    __shared__ float red[8];
    if ((t & 63) == 0) { red[t >> 6] = s; red[4 + (t >> 6)] = s2; }
    __syncthreads();
    s  = red[0] + red[1] + red[2] + red[3];
    s2 = red[4] + red[5] + red[6] + red[7];
    float mu  = s * (1.0f / 1024.0f);
    float var = fmaxf(s2 * (1.0f / 1024.0f) - mu * mu, 0.0f);
    float rstd = rsqrtf(var + 1e-5f);
    float4 g  = ((const float4*)gamma)[t];
    float4 bb = ((const float4*)beta)[t];
    ushort4 o;
    o.x = f2bf((v.x - mu) * rstd * g.x + bb.x);
    o.y = f2bf((v.y - mu) * rstd * g.y + bb.y);
    o.z = f2bf((v.z - mu) * rstd * g.z + bb.z);
    o.w = f2bf((v.w - mu) * rstd * g.w + bb.w);
    ((ushort4*)(h + (size_t)row * C))[t] = o;
}

// ---------------- fp32 -> bf16 cast ----------------
__global__ __launch_bounds__(256) void cast_bf16_kernel(
    const float* __restrict__ in, u16* __restrict__ o, int n4) {
    int i = blockIdx.x * blockDim.x + threadIdx.x;
    if (i >= n4) return;
    float4 v = ((const float4*)in)[i];
    ushort4 u;
    u.x = f2bf(v.x); u.y = f2bf(v.y); u.z = f2bf(v.z); u.w = f2bf(v.w);
    ((ushort4*)o)[i] = u;
}

// ---------------- GEMM: C[M,N] = A[M,K] * B[N,K]^T (both bf16 row-major) ----
// R13: T3-minimum 2-phase double-buffer (catalog §5.5 recipe): issue next
// tile's global_load_lds BEFORE current tile's ds_read+MFMA; ONE
// vmcnt(0)+barrier per K-step (emitted by __syncthreads). Buffer safety:
// reads of buf[cur] complete before the end-of-iter barrier, which precedes
// the next iteration's overwrite of buf[cur]. No swizzle/setprio (null at
// 2-phase per regime gate).
template<int WRITE_BF16>
__global__ __launch_bounds__(256) void gemm_bt(
    const u16* __restrict__ A, const u16* __restrict__ B,
    void* __restrict__ Cout, int M, int N, int K) {
    __shared__ u16 As[2][128 * 32];
    __shared__ u16 Bs[2][128 * 32];
    int t = threadIdx.x;
    int w = t >> 6;
    int l = t & 63;
    int lr = l & 15, lg = l >> 4;
    int mBase = blockIdx.y * 128;
    int nBase = blockIdx.x * 128;
    int wr = w >> 1, wc = w & 1;

    f32x4 zero = {0.f, 0.f, 0.f, 0.f};
    f32x4 acc[4][4];
#pragma unroll
    for (int i = 0; i < 4; i++)
#pragma unroll
        for (int j = 0; j < 4; j++) acc[i][j] = zero;

#define STAGE_G(buf, k0)                                                     \
    _Pragma("unroll")                                                        \
    for (int i = 0; i < 2; i++) {                                            \
        int fl = i * 256 + t;                                                \
        gload16(A + (size_t)(mBase + (fl >> 2)) * K + (k0) + (fl & 3) * 8,   \
                &As[buf][(size_t)(i * 256 + w * 64) * 8]);                   \
        gload16(B + (size_t)(nBase + (fl >> 2)) * K + (k0) + (fl & 3) * 8,   \
                &Bs[buf][(size_t)(i * 256 + w * 64) * 8]);                   \
    }

#define COMPUTE_G(buf)                                                       \
    {                                                                        \
        bf16x8 af[4], bfr[4];                                                \
        _Pragma("unroll")                                                    \
        for (int m2 = 0; m2 < 4; m2++)                                       \
            af[m2] = *(const bf16x8*)&As[buf][(wr*64 + m2*16 + lr)*32 + lg*8]; \
        _Pragma("unroll")                                                    \
        for (int n2 = 0; n2 < 4; n2++)                                       \
            bfr[n2] = *(const bf16x8*)&Bs[buf][(wc*64 + n2*16 + lr)*32 + lg*8]; \
        _Pragma("unroll")                                                    \
        for (int m2 = 0; m2 < 4; m2++)                                       \
            _Pragma("unroll")                                                \
            for (int n2 = 0; n2 < 4; n2++)                                   \
                acc[m2][n2] = __builtin_amdgcn_mfma_f32_16x16x32_bf16(       \
                    af[m2], bfr[n2], acc[m2][n2], 0, 0, 0);                  \
    }

    STAGE_G(0, 0);
    __syncthreads();
    int cur = 0;
    for (int k0 = 32; k0 < K; k0 += 32) {
        STAGE_G(cur ^ 1, k0);       // prefetch next tile (in flight over MFMA)
        COMPUTE_G(cur);
        __syncthreads();            // vmcnt(0)+lgkmcnt(0)+barrier: next ready
        cur ^= 1;
    }
    COMPUTE_G(cur);                 // last tile, no prefetch
#undef STAGE_G
#undef COMPUTE_G

#pragma unroll
    for (int m2 = 0; m2 < 4; m2++) {
#pragma unroll
        for (int i = 0; i < 4; i++) {
            int gr = mBase + wr * 64 + m2 * 16 + lg * 4 + i;
#pragma unroll
            for (int n2 = 0; n2 < 4; n2++) {
                int gc = nBase + wc * 64 + n2 * 16 + lr;
                float val = acc[m2][n2][i];
                if (WRITE_BF16)
                    ((u16*)Cout)[(size_t)gr * N + gc] = f2bf(val);
                else
                    ((float*)Cout)[(size_t)gr * N + gc] = val;
            }
        }
    }
}

// ---------------- Flash attention (causal), bf16, swapped-QK^T ----------------
// R12-verified: Q pre-scaled 0.125, T13 defer-max, tr_b16 PV, K XOR-swizzle.
// Unchanged this round.
__global__ __launch_bounds__(256) void attn_kernel(
    const u16* __restrict__ qkv, u16* __restrict__ o) {
    const int T = 2048;
    const int LD = 3072;
    __shared__ u16 Ksh[64 * 64];
    __shared__ u16 Vsh[64 * 64];

    int t = threadIdx.x;
    int w = t >> 6, l = t & 63;
    int lr = l & 15, g = l >> 4;
    int b = blockIdx.x >> 4, h = blockIdx.x & 15;
    int q0 = (31 - blockIdx.y) * 64;   // longest blocks launch first
    size_t base = (size_t)b * T * LD;
    const u16* Qp = qkv + base + h * 64;
    const u16* Kp = qkv + base + 1024 + h * 64;
    const u16* Vp = qkv + base + 2048 + h * 64;

    int qrow = q0 + w * 16 + lr;       // softmax row this lane owns
    // Q as B-operand, pre-scaled by 1/8 (exact: power-of-2 exponent shift)
    bf16x8 qf[2];
    {
        const u16* qr = Qp + (size_t)qrow * LD + g * 8;
        qf[0] = *(const bf16x8*)qr;
        qf[1] = *(const bf16x8*)(qr + 32);
#pragma unroll
        for (int j = 0; j < 8; j++) {
            qf[0][j] = (short)f2bf(bf2f((u16)qf[0][j]) * 0.125f);
            qf[1][j] = (short)f2bf(bf2f((u16)qf[1][j]) * 0.125f);
        }
    }

    f32x4 zero = {0.f, 0.f, 0.f, 0.f};
    f32x4 oacc[4];                      // oacc[db][i] = O[q0+w*16+4g+i][db*16+lr]
#pragma unroll
    for (int n = 0; n < 4; n++) oacc[n] = zero;
    float mrow = -INFINITY, lsum = 0.f;

    // staging geometry (per-lane global addresses; LDS bases are wave-uniform)
    int kr = w * 16 + (l >> 3);        // K row for issue i: kr + i*8
    int ks = l & 7;                    // K LDS chunk slot this lane fills
    int vr = l >> 1;                   // V row for issue i: i*32 + vr
    int vc = w * 16 + (l & 1) * 8;     // V d-offset
    lds_cu16 vtr = (lds_cu16)(Vsh + l * 4);   // linear b64 slot (R11-verified)

    for (int j0 = 0; j0 <= q0; j0 += 64) {
        __syncthreads();
#pragma unroll
        for (int i = 0; i < 2; i++) {
            int r = kr + i * 8;
            gload16(Kp + (size_t)(j0 + r) * LD + ((ks ^ (r & 7)) << 3),
                    Ksh + w * 1024 + i * 512);
            gload16(Vp + (size_t)(j0 + i * 32 + vr) * LD + vc,
                    Vsh + w * 1024 + i * 512);
        }
        __syncthreads();

        // S' = K Q^T : lane accumulates S[qrow][kv = j0 + 16n + 4g + i]
        f32x4 sv[4];
#pragma unroll
        for (int n = 0; n < 4; n++) sv[n] = zero;
#pragma unroll
        for (int c2 = 0; c2 < 2; c2++) {
#pragma unroll
            for (int n = 0; n < 4; n++) {
                int row = n * 16 + lr;
                int slot = (c2 * 4 + g) ^ (row & 7);
                bf16x8 kf = *(const bf16x8*)&Ksh[row * 64 + slot * 8];
                sv[n] = __builtin_amdgcn_mfma_f32_16x16x32_bf16(kf, qf[c2], sv[n], 0, 0, 0);
            }
        }

        // online softmax, per-lane for q = qrow (S already scaled via Q)
        float p[4][4];
        float tmax = -INFINITY;
        bool full = (j0 + 63 <= q0 + w * 16);
#pragma unroll
        for (int n = 0; n < 4; n++)
#pragma unroll
            for (int i = 0; i < 4; i++) {
                float val = sv[n][i];
                if (!full && (j0 + n * 16 + g * 4 + i > qrow)) val = -INFINITY;
                p[n][i] = val;
                tmax = fmaxf(tmax, val);
            }
        tmax = fmaxf(tmax, __shfl_xor(tmax, 16));
        tmax = fmaxf(tmax, __shfl_xor(tmax, 32));

        // T13 defer-max: skip rescale when row max grew by <= 8
        bool defer = __all(tmax - mrow <= 8.0f);
        float mnew = defer ? mrow : fmaxf(mrow, tmax);
        float rsum = 0.f;
#pragma unroll
        for (int n = 0; n < 4; n++)
#pragma unroll
            for (int i = 0; i < 4; i++) {
                float e = __expf(p[n][i] - mnew);
                p[n][i] = e;
                rsum += e;
            }
        rsum += __shfl_xor(rsum, 16);
        rsum += __shfl_xor(rsum, 32);
        if (defer) {
            lsum += rsum;
        } else {
            float alpha = __expf(mrow - mnew);
            lsum = lsum * alpha + rsum;
            mrow = mnew;
            float ao[4];
#pragma unroll
            for (int i = 0; i < 4; i++) ao[i] = __shfl(alpha, g * 4 + i);
#pragma unroll
            for (int db = 0; db < 4; db++)
#pragma unroll
                for (int i = 0; i < 4; i++) oacc[db][i] *= ao[i];
        }

        // pack P to bf16 A-fragments: slot j of pf0 holds kv 4g+j (n=0) and
        // 16+4g+j (n=1); pf1 the same +32 (k-permutation cancels with B).
        bf16x8 pf0, pf1;
#pragma unroll
        for (int j = 0; j < 4; j++) {
            pf0[j]     = (short)f2bf(p[0][j]);
            pf0[4 + j] = (short)f2bf(p[1][j]);
            pf1[j]     = (short)f2bf(p[2][j]);
            pf1[4 + j] = (short)f2bf(p[3][j]);
        }

        // O += P V ; V B-fragment via hardware-transpose reads (linear base)
#pragma unroll
        for (int db = 0; db < 4; db++) {
            bf16x4 t0, t1, t2, t3;
            asm volatile("ds_read_b64_tr_b16 %0, %1 offset:%2"
                         : "=v"(t0) : "v"(vtr), "i"(db * 2048 + 0));
            asm volatile("ds_read_b64_tr_b16 %0, %1 offset:%2"
                         : "=v"(t1) : "v"(vtr), "i"(db * 2048 + 512));
            asm volatile("ds_read_b64_tr_b16 %0, %1 offset:%2"
                         : "=v"(t2) : "v"(vtr), "i"(db * 2048 + 1024));
            asm volatile("ds_read_b64_tr_b16 %0, %1 offset:%2"
                         : "=v"(t3) : "v"(vtr), "i"(db * 2048 + 1536));
            asm volatile("s_waitcnt lgkmcnt(0)" ::: "memory");
            __builtin_amdgcn_sched_barrier(0);
            bf16x8 vb0, vb1;
#pragma unroll
            for (int j = 0; j < 4; j++) {
                vb0[j] = t0[j]; vb0[4 + j] = t1[j];
                vb1[j] = t2[j]; vb1[4 + j] = t3[j];
            }
            oacc[db] = __builtin_amdgcn_mfma_f32_16x16x32_bf16(pf0, vb0, oacc[db], 0, 0, 0);
            oacc[db] = __builtin_amdgcn_mfma_f32_16x16x32_bf16(pf1, vb1, oacc[db], 0, 0, 0);
        }
    }

    // epilogue: normalize + store (row q = q0+w*16+4g+i, col d = h*64+db*16+lr)
    float li[4];
#pragma unroll
    for (int i = 0; i < 4; i++) li[i] = 1.0f / __shfl(lsum, g * 4 + i);
#pragma unroll
    for (int db = 0; db < 4; db++)
#pragma unroll
        for (int i = 0; i < 4; i++) {
            int q = q0 + w * 16 + g * 4 + i;
            o[((size_t)b * T + q) * 1024 + h * 64 + db * 16 + lr] =
                f2bf(oacc[db][i] * li[i]);
        }
}

extern "C" void kernel_launch(void* const* d_in, const int* in_sizes, int n_in,
                              void* d_out, int out_size, void* d_ws, size_t ws_size,
                              hipStream_t stream) {
    const float* x     = (const float*)d_in[0];
    const float* gamma = (const float*)d_in[1];
    const float* beta  = (const float*)d_in[2];
    const float* wqkv  = (const float*)d_in[3];
    const float* wout  = (const float*)d_in[4];
    float* out = (float*)d_out;

    const int M = 8192;  // 4 * 2048
    char* ws = (char*)d_ws;
    u16* h     = (u16*)ws; ws += (size_t)M * 1024 * 2;
    u16* wqkvb = (u16*)ws; ws += (size_t)3072 * 1024 * 2;
    u16* woutb = (u16*)ws; ws += (size_t)1024 * 1024 * 2;
    u16* qkvb  = (u16*)ws; ws += (size_t)M * 3072 * 2;
    u16* attnb = (u16*)ws; ws += (size_t)M * 1024 * 2;

    ln_bf16_kernel<<<dim3(M), dim3(256), 0, stream>>>(x, gamma, beta, h);
    cast_bf16_kernel<<<dim3((3072 * 1024 / 4 + 255) / 256), dim3(256), 0, stream>>>(
        wqkv, wqkvb, 3072 * 1024 / 4);
    cast_bf16_kernel<<<dim3((1024 * 1024 / 4 + 255) / 256), dim3(256), 0, stream>>>(
        wout, woutb, 1024 * 1024 / 4);
    gemm_bt<1><<<dim3(24, 64), dim3(256), 0, stream>>>(h, wqkvb, (void*)qkvb, M, 3072, 1024);
    attn_kernel<<<dim3(64, 32), dim3(256), 0, stream>>>(qkvb, attnb);
    gemm_bt<0><<<dim3(8, 64), dim3(256), 0, stream>>>(attnb, woutb, (void*)out, M, 1024, 1024);
}